// Round 19
// baseline (479.007 us; speedup 1.0000x reference)
//
#include <hip/hip_runtime.h>
#include <hip/hip_bf16.h>

#define NN 50000
#define NE 600000
#define NG 64
#define PD 128
#define HD 256
#define NPAD 50048   // ceil(NN/64)*64
#define NBKT 32      // BN atomic buckets
#define CAP 64       // per-node edge bucket capacity (mean deg 12, max ~28)

// fused-front grid partition (BN | GN | SCAT | CVT)
#define NB_BN   2344   // ceil(NE/256)
#define NB_GN   391    // ceil(NN/128)
#define NB_SCAT 2344   // ceil(NE/256)
#define NB_CVT  128
// fused-big grid partition (GEMM | H)
#define NB_GEMM 2344   // ceil(NE/256), 4 tiles/block
#define NB_H    3125   // NN*PD/8/256

typedef __bf16 bf16;
typedef __bf16 bf16x8 __attribute__((ext_vector_type(8)));
typedef __bf16 bf16x4 __attribute__((ext_vector_type(4)));
typedef float f32x4 __attribute__((ext_vector_type(4)));

__device__ __forceinline__ float lrelu(float x) { return x > 0.f ? x : 0.01f * x; }

// ======== K1: fused front (bn_stats | gn_stats | bucket-scatter | convert) ========
__global__ __launch_bounds__(256) void k_front(const float* __restrict__ ea,
                                               const int* __restrict__ src,
                                               const int* __restrict__ dst,
                                               const float* __restrict__ x,
                                               const int* __restrict__ batch,
                                               const float* __restrict__ pw,
                                               const float* __restrict__ w1,
                                               const float* __restrict__ w2,
                                               float* __restrict__ colsum, float* __restrict__ colsq,
                                               float* __restrict__ gsum, float* __restrict__ gsq,
                                               int* __restrict__ gcnt,
                                               int* __restrict__ cnt, int2* __restrict__ es,
                                               bf16* __restrict__ pw16, bf16* __restrict__ w116,
                                               bf16* __restrict__ w216) {
    __shared__ f32x4 shA[256], shB[256];
    const int b = blockIdx.x, t = threadIdx.x;
    if (b < NB_BN) {
        const int cq = (t & 31) * 4;
        const int ro = t >> 5;
        const size_t base = (size_t)b * 256;
        f32x4 s = {0.f, 0.f, 0.f, 0.f}, q = {0.f, 0.f, 0.f, 0.f};
        for (int r0 = 0; r0 < 32; r0 += 8) {
            float4 v[8];
#pragma unroll
            for (int u = 0; u < 8; ++u) {
                size_t e = base + (size_t)(r0 + u) * 8 + ro;
                v[u] = (e < NE) ? *(const float4*)(ea + e * PD + cq)
                                : make_float4(0.f, 0.f, 0.f, 0.f);
            }
#pragma unroll
            for (int u = 0; u < 8; ++u) {
                s[0] += v[u].x; s[1] += v[u].y; s[2] += v[u].z; s[3] += v[u].w;
                q[0] += v[u].x * v[u].x; q[1] += v[u].y * v[u].y;
                q[2] += v[u].z * v[u].z; q[3] += v[u].w * v[u].w;
            }
        }
        shA[t] = s; shB[t] = q;
        __syncthreads();
        if (t < 128) { shA[t] += shA[t + 128]; shB[t] += shB[t + 128]; }
        __syncthreads();
        if (t < 64) { shA[t] += shA[t + 64]; shB[t] += shB[t + 64]; }
        __syncthreads();
        if (t < 32) {
            f32x4 a = shA[t] + shA[t + 32];
            f32x4 bb = shB[t] + shB[t + 32];
            const int bk = (b & (NBKT - 1)) * PD;
#pragma unroll
            for (int i = 0; i < 4; ++i) {
                atomicAdd(&colsum[bk + t * 4 + i], a[i]);
                atomicAdd(&colsq[bk + t * 4 + i], bb[i]);
            }
        }
    } else if (b < NB_BN + NB_GN) {
        const int p = t & 127, half = t >> 7;
        int base = (b - NB_BN) * 128 + half * 64;
        if (base >= NN) return;
        int end = min(base + 64, NN);
        float s = 0.f, q = 0.f;
        int cur = batch[base];
        int runstart = base;
        for (int i0 = base; i0 < end; i0 += 8) {
            float v[8];
            int g[8];
#pragma unroll
            for (int u = 0; u < 8; ++u) {
                int i = i0 + u;
                if (i < end) {
                    v[u] = x[(size_t)i * PD + p];
                    g[u] = batch[i];
                }
            }
#pragma unroll
            for (int u = 0; u < 8; ++u) {
                int i = i0 + u;
                if (i < end) {
                    if (g[u] != cur) {
                        atomicAdd(&gsum[cur * PD + p], s);
                        atomicAdd(&gsq[cur * PD + p], q);
                        if (p == 0) atomicAdd(&gcnt[cur], i - runstart);
                        s = 0.f; q = 0.f; cur = g[u]; runstart = i;
                    }
                    s += v[u]; q += v[u] * v[u];
                }
            }
        }
        atomicAdd(&gsum[cur * PD + p], s);
        atomicAdd(&gsq[cur * PD + p], q);
        if (p == 0) atomicAdd(&gcnt[cur], end - runstart);
    } else if (b < NB_BN + NB_GN + NB_SCAT) {
        int e = (b - NB_BN - NB_GN) * 256 + t;
        if (e < NE) {
            int d = dst[e];
            int pos = atomicAdd(&cnt[d], 1);
            if (pos < CAP) es[(size_t)d * CAP + pos] = make_int2(e, src[e]);
        }
    } else {
        int i = (b - NB_BN - NB_GN - NB_SCAT) * 256 + t;
        if (i < PD * PD) pw16[i] = (bf16)pw[i];
        if (i < HD * PD) w116[i] = (bf16)w1[i];
        if (i < PD * HD) w216[i] = (bf16)w2[i];
    }
}

// ======== K2: fused (bn_finalize(32-bucket) | gn_finalize), 33 blocks ========
__global__ __launch_bounds__(256) void k_mid(const float* __restrict__ colsum,
                                             const float* __restrict__ colsq,
                                             const float* __restrict__ bng,
                                             const float* __restrict__ bnb,
                                             float* __restrict__ escale, float* __restrict__ eshift,
                                             const float* __restrict__ gsum,
                                             const float* __restrict__ gsq,
                                             const int* __restrict__ gcnt,
                                             const float* __restrict__ gnw,
                                             const float* __restrict__ gnb,
                                             const float* __restrict__ gms,
                                             float* __restrict__ gA, float* __restrict__ gB) {
    const int b = blockIdx.x, t = threadIdx.x;
    if (b == 0) {
        if (t < 128) {
            float ms = 0.f, qs = 0.f;
#pragma unroll
            for (int k = 0; k < NBKT; ++k) {
                ms += colsum[k * PD + t];
                qs += colsq[k * PD + t];
            }
            float m = ms / (float)NE;
            float v = qs / (float)NE - m * m;
            float sc = bng[t] * rsqrtf(v + 1e-5f);
            escale[t] = sc;
            eshift[t] = bnb[t] - sc * m;
        }
    } else {
        int i = (b - 1) * 256 + t;
        if (i < NG * PD) {
            int p = i & (PD - 1);
            float c = (float)max(gcnt[i >> 7], 1);
            float m = gsum[i] / c;
            float q = gsq[i] / c;
            float s = gms[p];
            float var = q - m * m * (2.f * s - s * s);
            float inv = rsqrtf(var + 1e-5f);
            float a = gnw[p] * inv;
            gA[i] = a;
            gB[i] = gnb[p] - a * s * m;
        }
    }
}

// ======== K_BIG: fused (edge_gemm depth-2 pipeline | compute_h) ========
template <bool STORE16>
__global__ __launch_bounds__(256) void k_big(const float* __restrict__ ea,
                                             const float* __restrict__ escale,
                                             const float* __restrict__ eshift,
                                             const bf16* __restrict__ pw16,
                                             const float* __restrict__ pass_b,
                                             bf16* __restrict__ attr16,
                                             float* __restrict__ out1,
                                             const float* __restrict__ x,
                                             const int* __restrict__ batch,
                                             const float* __restrict__ gA,
                                             const float* __restrict__ gB,
                                             bf16* __restrict__ h16) {
    const int b = blockIdx.x, t = threadIdx.x;
    if (b < NB_GEMM) {
        __shared__ __align__(16) bf16 T[4][16 * PD];       // 16 KB
        __shared__ __align__(16) float T2[4][16 * 132];    // 33.8 KB raw ea tile (row pad 132)
        const int wave = t >> 6, lane = t & 63, g = lane >> 4, li = lane & 15;
        const int base = b * 256;
        const int ntiles = min(4, (NE - base) >> 6);
        // depth-2 prefetch registers: A = tile it, B = tile it+1
        float4 vA0[4], vA1[4], vB0[4], vB1[4];
        {
            const float* rp = ea + (size_t)(base + wave * 16 + li) * PD;
#pragma unroll
            for (int ks = 0; ks < 4; ++ks) {
                const int kb = ks * 32 + g * 8;
                vA0[ks] = *(const float4*)(rp + kb);
                vA1[ks] = *(const float4*)(rp + kb + 4);
            }
        }
        if (ntiles > 1) {
            const float* rp = ea + (size_t)(base + 64 + wave * 16 + li) * PD;
#pragma unroll
            for (int ks = 0; ks < 4; ++ks) {
                const int kb = ks * 32 + g * 8;
                vB0[ks] = *(const float4*)(rp + kb);
                vB1[ks] = *(const float4*)(rp + kb + 4);
            }
        }
        for (int it = 0; it < ntiles; ++it) {
            const int e0 = base + it * 64 + wave * 16;
            float4 vC0[4], vC1[4];
            const bool more2 = (it + 2 < ntiles);
            if (more2) {
                const float* rp = ea + (size_t)(e0 + 128 + li) * PD;
#pragma unroll
                for (int ks = 0; ks < 4; ++ks) {
                    const int kb = ks * 32 + g * 8;
                    vC0[ks] = *(const float4*)(rp + kb);
                    vC1[ks] = *(const float4*)(rp + kb + 4);
                }
            }
            bf16x8 af[4];
#pragma unroll
            for (int ks = 0; ks < 4; ++ks) {
                const int kb = ks * 32 + g * 8;
                // stage raw ea into padded LDS (for the out1 epilogue; wave-private)
                *(float4*)&T2[wave][li * 132 + kb] = vA0[ks];
                *(float4*)&T2[wave][li * 132 + kb + 4] = vA1[ks];
                float4 s0 = *(const float4*)(escale + kb);
                float4 s1 = *(const float4*)(escale + kb + 4);
                float4 f0 = *(const float4*)(eshift + kb);
                float4 f1 = *(const float4*)(eshift + kb + 4);
                bf16x8 pk;
                pk[0] = (bf16)lrelu(fmaf(s0.x, vA0[ks].x, f0.x));
                pk[1] = (bf16)lrelu(fmaf(s0.y, vA0[ks].y, f0.y));
                pk[2] = (bf16)lrelu(fmaf(s0.z, vA0[ks].z, f0.z));
                pk[3] = (bf16)lrelu(fmaf(s0.w, vA0[ks].w, f0.w));
                pk[4] = (bf16)lrelu(fmaf(s1.x, vA1[ks].x, f1.x));
                pk[5] = (bf16)lrelu(fmaf(s1.y, vA1[ks].y, f1.y));
                pk[6] = (bf16)lrelu(fmaf(s1.z, vA1[ks].z, f1.z));
                pk[7] = (bf16)lrelu(fmaf(s1.w, vA1[ks].w, f1.w));
                af[ks] = pk;
            }
            f32x4 acc[8];
#pragma unroll
            for (int ct = 0; ct < 8; ++ct) acc[ct] = f32x4{0.f, 0.f, 0.f, 0.f};
#pragma unroll
            for (int ks = 0; ks < 4; ++ks) {
                const int kb = ks * 32 + g * 8;
#pragma unroll
                for (int ct = 0; ct < 8; ++ct) {
                    const int col = (ct << 4) + li;
                    bf16x8 bfr = *(const bf16x8*)(pw16 + col * PD + kb);
                    acc[ct] = __builtin_amdgcn_mfma_f32_16x16x32_bf16(af[ks], bfr, acc[ct], 0, 0, 0);
                }
            }
#pragma unroll
            for (int ct = 0; ct < 8; ++ct) {
                const int col = (ct << 4) + li;
                const float pb = pass_b[col];
#pragma unroll
                for (int j = 0; j < 4; ++j) {
                    T[wave][(((g << 2) + j) << 7) + col] = (bf16)(acc[ct][j] + pb);
                }
            }
            const size_t gbase = (size_t)e0 * PD;
            if (STORE16) {
#pragma unroll
                for (int i = 0; i < 4; ++i) {
                    const int idx = i * 512 + lane * 8;
                    __builtin_nontemporal_store(*(const bf16x8*)&T[wave][idx],
                                                (bf16x8*)(attr16 + gbase + idx));
                }
            }
#pragma unroll
            for (int i = 0; i < 8; ++i) {
                const int idx = i * 256 + lane * 4;
                const int row = idx >> 7, col = idx & 127;
                bf16x4 a = *(const bf16x4*)&T[wave][idx];
                float4 e0v = *(const float4*)&T2[wave][row * 132 + col];
                f32x4 w = {(float)a[0] + e0v.x, (float)a[1] + e0v.y,
                           (float)a[2] + e0v.z, (float)a[3] + e0v.w};
                __builtin_nontemporal_store(w, (f32x4*)(out1 + gbase + idx));
            }
            // rotate: A <- B, B <- C
#pragma unroll
            for (int ks = 0; ks < 4; ++ks) {
                vA0[ks] = vB0[ks]; vA1[ks] = vB1[ks];
                if (more2) { vB0[ks] = vC0[ks]; vB1[ks] = vC1[ks]; }
            }
        }
    } else {
        int i = (b - NB_GEMM) * 256 + t;  // over NN*PD/8
        int node = i >> 4;
        int cb = (i & 15) * 8;
        int g = batch[node];
        const float* xp = x + (size_t)node * PD + cb;
        float4 v0 = *(const float4*)xp;
        float4 v1 = *(const float4*)(xp + 4);
        const float* ap = gA + g * PD + cb;
        const float* bp = gB + g * PD + cb;
        float4 a0 = *(const float4*)ap, a1 = *(const float4*)(ap + 4);
        float4 b0 = *(const float4*)bp, b1 = *(const float4*)(bp + 4);
        bf16x8 pk;
        pk[0] = (bf16)lrelu(fmaf(a0.x, v0.x, b0.x));
        pk[1] = (bf16)lrelu(fmaf(a0.y, v0.y, b0.y));
        pk[2] = (bf16)lrelu(fmaf(a0.z, v0.z, b0.z));
        pk[3] = (bf16)lrelu(fmaf(a0.w, v0.w, b0.w));
        pk[4] = (bf16)lrelu(fmaf(a1.x, v1.x, b1.x));
        pk[5] = (bf16)lrelu(fmaf(a1.y, v1.y, b1.y));
        pk[6] = (bf16)lrelu(fmaf(a1.z, v1.z, b1.z));
        pk[7] = (bf16)lrelu(fmaf(a1.w, v1.w, b1.w));
        *(bf16x8*)(h16 + (size_t)i * 8) = pk;
    }
}

// ======== per-node softmax aggregation (fixed-cap buckets, no-max, depth-6) ========
__global__ __launch_bounds__(128) void k_aggregate(const int2* __restrict__ es,
                                                   const int* __restrict__ cnt,
                                                   const bf16* __restrict__ h,
                                                   const bf16* __restrict__ attr16,
                                                   const float* __restrict__ tptr,
                                                   bf16* __restrict__ outpre) {
    const int node = blockIdx.x;
    const int p = threadIdx.x;
    const float tv = tptr[0];
    const size_t o = (size_t)node * CAP;
    const int d = min(cnt[node], CAP);
    float denE = 0.f, numE = 0.f, denO = 0.f, numO = 0.f;
    float a0 = 0.f, h0 = 0.f, a1 = 0.f, h1 = 0.f, a2 = 0.f, h2 = 0.f;
    float a3 = 0.f, h3 = 0.f, a4 = 0.f, h4 = 0.f, a5 = 0.f, h5 = 0.f;
#define LOADJ(A, H, J)                                                   \
    if ((J) < d) {                                                       \
        int2 q = es[o + (J)];                                            \
        A = (float)attr16[(size_t)q.x * PD + p];                         \
        H = (float)h[(size_t)q.y * PD + p];                              \
    }
    LOADJ(a0, h0, 0) LOADJ(a1, h1, 1) LOADJ(a2, h2, 2)
    LOADJ(a3, h3, 3) LOADJ(a4, h4, 4) LOADJ(a5, h5, 5)
    for (int j = 0; j < d; ++j) {
        float av = a0, hv = h0;
        a0 = a1; h0 = h1;
        a1 = a2; h1 = h2;
        a2 = a3; h2 = h3;
        a3 = a4; h3 = h4;
        a4 = a5; h4 = h5;
        if (j + 6 < d) {
            int2 q = es[o + j + 6];
            a5 = (float)attr16[(size_t)q.x * PD + p];
            h5 = (float)h[(size_t)q.y * PD + p];
        }
        float msg = hv + av;
        msg = (msg > 0.f ? msg : 0.f) + 1e-7f;
        float w = __expf(msg * tv);
        if (j & 1) { denO += w; numO += msg * w; }
        else       { denE += w; numE += msg * w; }
    }
#undef LOADJ
    float hv = (float)h[(size_t)node * PD + p];
    float agg = (d > 0) ? (numE + numO) / (denE + denO) : 0.f;
    outpre[(size_t)node * PD + p] = (bf16)(agg + hv);
}

// fallback (small workspace): recover attr = out1 - ea
__global__ __launch_bounds__(128) void k_aggregateF(const int2* __restrict__ es,
                                                    const int* __restrict__ cnt,
                                                    const bf16* __restrict__ h,
                                                    const float* __restrict__ out1,
                                                    const float* __restrict__ ea,
                                                    const float* __restrict__ tptr,
                                                    bf16* __restrict__ outpre) {
    const int node = blockIdx.x;
    const int p = threadIdx.x;
    const float tv = tptr[0];
    const size_t o = (size_t)node * CAP;
    const int d = min(cnt[node], CAP);
    float den = 0.f, num = 0.f;
    for (int j = 0; j < d; ++j) {
        int2 q = es[o + j];
        size_t idx = (size_t)q.x * PD + p;
        float av = out1[idx] - ea[idx];
        float msg = (float)h[(size_t)q.y * PD + p] + av;
        msg = (msg > 0.f ? msg : 0.f) + 1e-7f;
        float w = __expf(msg * tv);
        den += w;
        num += msg * w;
    }
    float hv = (float)h[(size_t)node * PD + p];
    float agg = (d > 0) ? num / den : 0.f;
    outpre[(size_t)node * PD + p] = (bf16)(agg + hv);
}

// ======== MLP: out0 = relu(LN(outpre @ W1^T)) @ W2^T + x ========
__global__ __launch_bounds__(256) void k_mlp(const bf16* __restrict__ outpre,
                                             const bf16* __restrict__ w116,
                                             const bf16* __restrict__ w216,
                                             const float* __restrict__ lng,
                                             const float* __restrict__ lnb,
                                             const float* __restrict__ x,
                                             float* __restrict__ out0) {
    __shared__ __align__(16) float SM[64][132];  // aliased as A2 (64x256 bf16)
    bf16* A2 = (bf16*)&SM[0][0];
    const int t = threadIdx.x, wave = t >> 6, lane = t & 63, g = lane >> 4, li = lane & 15;
    const size_t n0 = (size_t)blockIdx.x * 64;
    const int arow = (wave << 4) + li;
    f32x4 accY[16];
#pragma unroll
    for (int ct = 0; ct < 16; ++ct) accY[ct] = f32x4{0.f, 0.f, 0.f, 0.f};
#pragma unroll
    for (int ks = 0; ks < 4; ++ks) {
        int kb = ks * 32 + g * 8;
        bf16x8 af = *(const bf16x8*)(outpre + (n0 + arow) * PD + kb);
#pragma unroll
        for (int ct = 0; ct < 16; ++ct) {
            int col = (ct << 4) + li;
            bf16x8 bfr = *(const bf16x8*)(w116 + col * PD + kb);
            accY[ct] = __builtin_amdgcn_mfma_f32_16x16x32_bf16(af, bfr, accY[ct], 0, 0, 0);
        }
    }
#pragma unroll
    for (int j = 0; j < 4; ++j) {
        float s1 = 0.f, s2 = 0.f;
#pragma unroll
        for (int ct = 0; ct < 16; ++ct) {
            float v = accY[ct][j];
            s1 += v; s2 += v * v;
        }
        for (int o = 1; o < 16; o <<= 1) {
            s1 += __shfl_xor(s1, o);
            s2 += __shfl_xor(s2, o);
        }
        float mean = s1 * (1.f / HD);
        float var = s2 * (1.f / HD) - mean * mean;
        float rstd = rsqrtf(var + 1e-5f);
        int row = (wave << 4) + (g << 2) + j;
#pragma unroll
        for (int ct = 0; ct < 16; ++ct) {
            int col = (ct << 4) + li;
            float v = (accY[ct][j] - mean) * rstd;
            v = lng[col] * v + lnb[col];
            v = v > 0.f ? v : 0.f;
            A2[(row << 8) + (col ^ ((row & 7) << 3))] = (bf16)v;
        }
    }
    __syncthreads();
    f32x4 accZ[8];
#pragma unroll
    for (int ct = 0; ct < 8; ++ct) accZ[ct] = f32x4{0.f, 0.f, 0.f, 0.f};
#pragma unroll
    for (int ks = 0; ks < 8; ++ks) {
        int kb = ks * 32 + g * 8;
        bf16x8 af = *(const bf16x8*)&A2[(arow << 8) + (kb ^ ((arow & 7) << 3))];
#pragma unroll
        for (int ct = 0; ct < 8; ++ct) {
            int col = (ct << 4) + li;
            bf16x8 bfr = *(const bf16x8*)(w216 + col * HD + kb);
            accZ[ct] = __builtin_amdgcn_mfma_f32_16x16x32_bf16(af, bfr, accZ[ct], 0, 0, 0);
        }
    }
    __syncthreads();  // done reading A2
#pragma unroll
    for (int ct = 0; ct < 8; ++ct) {
        int col = (ct << 4) + li;
#pragma unroll
        for (int j = 0; j < 4; ++j) {
            int row = (wave << 4) + (g << 2) + j;
            SM[row][col] = accZ[ct][j];
        }
    }
    __syncthreads();
    {
        const size_t gb = n0 * PD;
#pragma unroll
        for (int i = 0; i < 8; ++i) {
            const int idx = i * 1024 + t * 4;
            const int row = idx >> 7, col = idx & 127;
            const size_t n = n0 + row;
            if (n < NN) {
                float4 r = *(const float4*)&SM[row][col];
                float4 xv = *(const float4*)(x + gb + idx);
                float4 w = {r.x + xv.x, r.y + xv.y, r.z + xv.z, r.w + xv.w};
                *(float4*)(out0 + gb + idx) = w;
            }
        }
    }
}

extern "C" void kernel_launch(void* const* d_in, const int* in_sizes, int n_in,
                              void* d_out, int out_size, void* d_ws, size_t ws_size,
                              hipStream_t stream) {
    const float* x = (const float*)d_in[0];
    const int* ei = (const int*)d_in[1];
    const float* ea = (const float*)d_in[2];
    const int* batch = (const int*)d_in[3];
    const float* gnw = (const float*)d_in[4];
    const float* gnb = (const float*)d_in[5];
    const float* gms = (const float*)d_in[6];
    const float* bng = (const float*)d_in[7];
    const float* bnb = (const float*)d_in[8];
    const float* pW = (const float*)d_in[9];
    const float* pb = (const float*)d_in[10];
    const float* tp = (const float*)d_in[11];
    const float* W1 = (const float*)d_in[12];
    const float* lng = (const float*)d_in[13];
    const float* lnb = (const float*)d_in[14];
    const float* W2 = (const float*)d_in[15];
    const int* srcI = ei;
    const int* dstI = ei + NE;
    float* out0 = (float*)d_out;
    float* out1 = out0 + (size_t)NN * PD;

    char* w = (char*)d_ws;
    size_t off = 0;
    auto alloc = [&](size_t bytes) -> char* {
        char* p = w + off;
        off += (bytes + 255) & ~(size_t)255;
        return p;
    };
    float* colsum = (float*)alloc(NBKT * PD * 4);
    float* colsq = (float*)alloc(NBKT * PD * 4);
    float* gsum = (float*)alloc(NG * PD * 4);
    float* gsq = (float*)alloc(NG * PD * 4);
    int* gcnt = (int*)alloc(NG * 4);
    int* cnt = (int*)alloc(NN * 4);
    size_t zero_bytes = off;  // everything above zeroed each call
    int2* es = (int2*)alloc((size_t)NN * CAP * 8);
    float* gA = (float*)alloc(NG * PD * 4);
    float* gB = (float*)alloc(NG * PD * 4);
    float* escale = (float*)alloc(PD * 4);
    float* eshift = (float*)alloc(PD * 4);
    bf16* pw16 = (bf16*)alloc(PD * PD * 2);
    bf16* w116 = (bf16*)alloc(HD * PD * 2);
    bf16* w216 = (bf16*)alloc(PD * HD * 2);
    bf16* h16 = (bf16*)alloc((size_t)NN * PD * 2);
    bf16* outpre = (bf16*)alloc((size_t)NPAD * PD * 2);
    size_t small_total = off;
    bf16* attr16 = (bf16*)alloc((size_t)NE * PD * 2);
    size_t big_total = off;
    if (ws_size < small_total) return;  // cannot run
    const bool big = (ws_size >= big_total);

    hipMemsetAsync(d_ws, 0, zero_bytes, stream);
    k_front<<<NB_BN + NB_GN + NB_SCAT + NB_CVT, 256, 0, stream>>>(
        ea, srcI, dstI, x, batch, pW, W1, W2, colsum, colsq, gsum, gsq, gcnt, cnt, es,
        pw16, w116, w216);
    k_mid<<<33, 256, 0, stream>>>(colsum, colsq, bng, bnb, escale, eshift,
                                  gsum, gsq, gcnt, gnw, gnb, gms, gA, gB);
    if (big) {
        k_big<true><<<NB_GEMM + NB_H, 256, 0, stream>>>(
            ea, escale, eshift, pw16, pb, attr16, out1, x, batch, gA, gB, h16);
        k_aggregate<<<NN, 128, 0, stream>>>(es, cnt, h16, attr16, tp, outpre);
    } else {
        k_big<false><<<NB_GEMM + NB_H, 256, 0, stream>>>(
            ea, escale, eshift, pw16, pb, nullptr, out1, x, batch, gA, gB, h16);
        k_aggregateF<<<NN, 128, 0, stream>>>(es, cnt, h16, out1, ea, tp, outpre);
    }
    k_mlp<<<NPAD / 64, 256, 0, stream>>>(outpre, w116, w216, lng, lnb, x, out0);
}

// Round 20
// 418.959 us; speedup vs baseline: 1.1433x; 1.1433x over previous
//
#include <hip/hip_runtime.h>
#include <hip/hip_bf16.h>

#define NN 50000
#define NE 600000
#define NG 64
#define PD 128
#define HD 256
#define NPAD 50048   // ceil(NN/64)*64
#define NBKT 32      // BN atomic buckets
#define CAP 64       // per-node edge bucket capacity (mean deg 12, max ~28)

// fused-front grid partition (BN | GN | SCAT | CVT)
#define NB_BN   2344   // ceil(NE/256)
#define NB_GN   391    // ceil(NN/128)
#define NB_SCAT 2344   // ceil(NE/256)
#define NB_CVT  128
// fused-big grid partition (GEMM | H)
#define NB_GEMM 2344   // ceil(NE/256), 4 tiles/block
#define NB_H    3125   // NN*PD/8/256

typedef __bf16 bf16;
typedef __bf16 bf16x8 __attribute__((ext_vector_type(8)));
typedef __bf16 bf16x4 __attribute__((ext_vector_type(4)));
typedef float f32x4 __attribute__((ext_vector_type(4)));

__device__ __forceinline__ float lrelu(float x) { return x > 0.f ? x : 0.01f * x; }
__device__ __forceinline__ float bf_lo(unsigned v) { return __uint_as_float(v << 16); }
__device__ __forceinline__ float bf_hi(unsigned v) { return __uint_as_float(v & 0xffff0000u); }

// ======== K1: fused front (bn_stats | gn_stats | bucket-scatter | convert) ========
__global__ __launch_bounds__(256) void k_front(const float* __restrict__ ea,
                                               const int* __restrict__ src,
                                               const int* __restrict__ dst,
                                               const float* __restrict__ x,
                                               const int* __restrict__ batch,
                                               const float* __restrict__ pw,
                                               const float* __restrict__ w1,
                                               const float* __restrict__ w2,
                                               float* __restrict__ colsum, float* __restrict__ colsq,
                                               float* __restrict__ gsum, float* __restrict__ gsq,
                                               int* __restrict__ gcnt,
                                               int* __restrict__ cnt, int2* __restrict__ es,
                                               bf16* __restrict__ pw16, bf16* __restrict__ w116,
                                               bf16* __restrict__ w216) {
    __shared__ f32x4 shA[256], shB[256];
    const int b = blockIdx.x, t = threadIdx.x;
    if (b < NB_BN) {
        const int cq = (t & 31) * 4;
        const int ro = t >> 5;
        const size_t base = (size_t)b * 256;
        f32x4 s = {0.f, 0.f, 0.f, 0.f}, q = {0.f, 0.f, 0.f, 0.f};
        for (int r0 = 0; r0 < 32; r0 += 8) {
            float4 v[8];
#pragma unroll
            for (int u = 0; u < 8; ++u) {
                size_t e = base + (size_t)(r0 + u) * 8 + ro;
                v[u] = (e < NE) ? *(const float4*)(ea + e * PD + cq)
                                : make_float4(0.f, 0.f, 0.f, 0.f);
            }
#pragma unroll
            for (int u = 0; u < 8; ++u) {
                s[0] += v[u].x; s[1] += v[u].y; s[2] += v[u].z; s[3] += v[u].w;
                q[0] += v[u].x * v[u].x; q[1] += v[u].y * v[u].y;
                q[2] += v[u].z * v[u].z; q[3] += v[u].w * v[u].w;
            }
        }
        shA[t] = s; shB[t] = q;
        __syncthreads();
        if (t < 128) { shA[t] += shA[t + 128]; shB[t] += shB[t + 128]; }
        __syncthreads();
        if (t < 64) { shA[t] += shA[t + 64]; shB[t] += shB[t + 64]; }
        __syncthreads();
        if (t < 32) {
            f32x4 a = shA[t] + shA[t + 32];
            f32x4 bb = shB[t] + shB[t + 32];
            const int bk = (b & (NBKT - 1)) * PD;
#pragma unroll
            for (int i = 0; i < 4; ++i) {
                atomicAdd(&colsum[bk + t * 4 + i], a[i]);
                atomicAdd(&colsq[bk + t * 4 + i], bb[i]);
            }
        }
    } else if (b < NB_BN + NB_GN) {
        const int p = t & 127, half = t >> 7;
        int base = (b - NB_BN) * 128 + half * 64;
        if (base >= NN) return;
        int end = min(base + 64, NN);
        float s = 0.f, q = 0.f;
        int cur = batch[base];
        int runstart = base;
        for (int i0 = base; i0 < end; i0 += 8) {
            float v[8];
            int g[8];
#pragma unroll
            for (int u = 0; u < 8; ++u) {
                int i = i0 + u;
                if (i < end) {
                    v[u] = x[(size_t)i * PD + p];
                    g[u] = batch[i];
                }
            }
#pragma unroll
            for (int u = 0; u < 8; ++u) {
                int i = i0 + u;
                if (i < end) {
                    if (g[u] != cur) {
                        atomicAdd(&gsum[cur * PD + p], s);
                        atomicAdd(&gsq[cur * PD + p], q);
                        if (p == 0) atomicAdd(&gcnt[cur], i - runstart);
                        s = 0.f; q = 0.f; cur = g[u]; runstart = i;
                    }
                    s += v[u]; q += v[u] * v[u];
                }
            }
        }
        atomicAdd(&gsum[cur * PD + p], s);
        atomicAdd(&gsq[cur * PD + p], q);
        if (p == 0) atomicAdd(&gcnt[cur], end - runstart);
    } else if (b < NB_BN + NB_GN + NB_SCAT) {
        int e = (b - NB_BN - NB_GN) * 256 + t;
        if (e < NE) {
            int d = dst[e];
            int pos = atomicAdd(&cnt[d], 1);
            if (pos < CAP) es[(size_t)d * CAP + pos] = make_int2(e, src[e]);
        }
    } else {
        int i = (b - NB_BN - NB_GN - NB_SCAT) * 256 + t;
        if (i < PD * PD) pw16[i] = (bf16)pw[i];
        if (i < HD * PD) w116[i] = (bf16)w1[i];
        if (i < PD * HD) w216[i] = (bf16)w2[i];
    }
}

// ======== K2: fused (bn_finalize(32-bucket) | gn_finalize), 33 blocks ========
__global__ __launch_bounds__(256) void k_mid(const float* __restrict__ colsum,
                                             const float* __restrict__ colsq,
                                             const float* __restrict__ bng,
                                             const float* __restrict__ bnb,
                                             float* __restrict__ escale, float* __restrict__ eshift,
                                             const float* __restrict__ gsum,
                                             const float* __restrict__ gsq,
                                             const int* __restrict__ gcnt,
                                             const float* __restrict__ gnw,
                                             const float* __restrict__ gnb,
                                             const float* __restrict__ gms,
                                             float* __restrict__ gA, float* __restrict__ gB) {
    const int b = blockIdx.x, t = threadIdx.x;
    if (b == 0) {
        if (t < 128) {
            float ms = 0.f, qs = 0.f;
#pragma unroll
            for (int k = 0; k < NBKT; ++k) {
                ms += colsum[k * PD + t];
                qs += colsq[k * PD + t];
            }
            float m = ms / (float)NE;
            float v = qs / (float)NE - m * m;
            float sc = bng[t] * rsqrtf(v + 1e-5f);
            escale[t] = sc;
            eshift[t] = bnb[t] - sc * m;
        }
    } else {
        int i = (b - 1) * 256 + t;
        if (i < NG * PD) {
            int p = i & (PD - 1);
            float c = (float)max(gcnt[i >> 7], 1);
            float m = gsum[i] / c;
            float q = gsq[i] / c;
            float s = gms[p];
            float var = q - m * m * (2.f * s - s * s);
            float inv = rsqrtf(var + 1e-5f);
            float a = gnw[p] * inv;
            gA[i] = a;
            gB[i] = gnb[p] - a * s * m;
        }
    }
}

// ======== K_BIG: fused (edge_gemm | compute_h); ea staged in LDS (R18 depth-1 body) ========
template <bool STORE16>
__global__ __launch_bounds__(256) void k_big(const float* __restrict__ ea,
                                             const float* __restrict__ escale,
                                             const float* __restrict__ eshift,
                                             const bf16* __restrict__ pw16,
                                             const float* __restrict__ pass_b,
                                             bf16* __restrict__ attr16,
                                             float* __restrict__ out1,
                                             const float* __restrict__ x,
                                             const int* __restrict__ batch,
                                             const float* __restrict__ gA,
                                             const float* __restrict__ gB,
                                             bf16* __restrict__ h16) {
    const int b = blockIdx.x, t = threadIdx.x;
    if (b < NB_GEMM) {
        __shared__ __align__(16) bf16 T[4][16 * PD];       // 16 KB
        __shared__ __align__(16) float T2[4][16 * 132];    // 33.8 KB raw ea tile (row pad 132)
        const int wave = t >> 6, lane = t & 63, g = lane >> 4, li = lane & 15;
        const int base = b * 256;
        const int ntiles = min(4, (NE - base) >> 6);
        float4 v0[4], v1[4];
        {
            const float* rp = ea + (size_t)(base + wave * 16 + li) * PD;
#pragma unroll
            for (int ks = 0; ks < 4; ++ks) {
                const int kb = ks * 32 + g * 8;
                v0[ks] = *(const float4*)(rp + kb);
                v1[ks] = *(const float4*)(rp + kb + 4);
            }
        }
        for (int it = 0; it < ntiles; ++it) {
            const int e0 = base + it * 64 + wave * 16;
            float4 n0[4], n1[4];
            const bool more = (it + 1 < ntiles);
            if (more) {
                const float* rp = ea + (size_t)(e0 + 64 + li) * PD;
#pragma unroll
                for (int ks = 0; ks < 4; ++ks) {
                    const int kb = ks * 32 + g * 8;
                    n0[ks] = *(const float4*)(rp + kb);
                    n1[ks] = *(const float4*)(rp + kb + 4);
                }
            }
            bf16x8 af[4];
#pragma unroll
            for (int ks = 0; ks < 4; ++ks) {
                const int kb = ks * 32 + g * 8;
                *(float4*)&T2[wave][li * 132 + kb] = v0[ks];
                *(float4*)&T2[wave][li * 132 + kb + 4] = v1[ks];
                float4 s0 = *(const float4*)(escale + kb);
                float4 s1 = *(const float4*)(escale + kb + 4);
                float4 f0 = *(const float4*)(eshift + kb);
                float4 f1 = *(const float4*)(eshift + kb + 4);
                bf16x8 pk;
                pk[0] = (bf16)lrelu(fmaf(s0.x, v0[ks].x, f0.x));
                pk[1] = (bf16)lrelu(fmaf(s0.y, v0[ks].y, f0.y));
                pk[2] = (bf16)lrelu(fmaf(s0.z, v0[ks].z, f0.z));
                pk[3] = (bf16)lrelu(fmaf(s0.w, v0[ks].w, f0.w));
                pk[4] = (bf16)lrelu(fmaf(s1.x, v1[ks].x, f1.x));
                pk[5] = (bf16)lrelu(fmaf(s1.y, v1[ks].y, f1.y));
                pk[6] = (bf16)lrelu(fmaf(s1.z, v1[ks].z, f1.z));
                pk[7] = (bf16)lrelu(fmaf(s1.w, v1[ks].w, f1.w));
                af[ks] = pk;
            }
            f32x4 acc[8];
#pragma unroll
            for (int ct = 0; ct < 8; ++ct) acc[ct] = f32x4{0.f, 0.f, 0.f, 0.f};
#pragma unroll
            for (int ks = 0; ks < 4; ++ks) {
                const int kb = ks * 32 + g * 8;
#pragma unroll
                for (int ct = 0; ct < 8; ++ct) {
                    const int col = (ct << 4) + li;
                    bf16x8 bfr = *(const bf16x8*)(pw16 + col * PD + kb);
                    acc[ct] = __builtin_amdgcn_mfma_f32_16x16x32_bf16(af[ks], bfr, acc[ct], 0, 0, 0);
                }
            }
#pragma unroll
            for (int ct = 0; ct < 8; ++ct) {
                const int col = (ct << 4) + li;
                const float pb = pass_b[col];
#pragma unroll
                for (int j = 0; j < 4; ++j) {
                    T[wave][(((g << 2) + j) << 7) + col] = (bf16)(acc[ct][j] + pb);
                }
            }
            const size_t gbase = (size_t)e0 * PD;
            if (STORE16) {
#pragma unroll
                for (int i = 0; i < 4; ++i) {
                    const int idx = i * 512 + lane * 8;
                    __builtin_nontemporal_store(*(const bf16x8*)&T[wave][idx],
                                                (bf16x8*)(attr16 + gbase + idx));
                }
            }
#pragma unroll
            for (int i = 0; i < 8; ++i) {
                const int idx = i * 256 + lane * 4;
                const int row = idx >> 7, col = idx & 127;
                bf16x4 a = *(const bf16x4*)&T[wave][idx];
                float4 e0v = *(const float4*)&T2[wave][row * 132 + col];
                f32x4 w = {(float)a[0] + e0v.x, (float)a[1] + e0v.y,
                           (float)a[2] + e0v.z, (float)a[3] + e0v.w};
                __builtin_nontemporal_store(w, (f32x4*)(out1 + gbase + idx));
            }
            if (more) {
#pragma unroll
                for (int ks = 0; ks < 4; ++ks) { v0[ks] = n0[ks]; v1[ks] = n1[ks]; }
            }
        }
    } else {
        int i = (b - NB_GEMM) * 256 + t;  // over NN*PD/8
        int node = i >> 4;
        int cb = (i & 15) * 8;
        int g = batch[node];
        const float* xp = x + (size_t)node * PD + cb;
        float4 v0 = *(const float4*)xp;
        float4 v1 = *(const float4*)(xp + 4);
        const float* ap = gA + g * PD + cb;
        const float* bp = gB + g * PD + cb;
        float4 a0 = *(const float4*)ap, a1 = *(const float4*)(ap + 4);
        float4 b0 = *(const float4*)bp, b1 = *(const float4*)(bp + 4);
        bf16x8 pk;
        pk[0] = (bf16)lrelu(fmaf(a0.x, v0.x, b0.x));
        pk[1] = (bf16)lrelu(fmaf(a0.y, v0.y, b0.y));
        pk[2] = (bf16)lrelu(fmaf(a0.z, v0.z, b0.z));
        pk[3] = (bf16)lrelu(fmaf(a0.w, v0.w, b0.w));
        pk[4] = (bf16)lrelu(fmaf(a1.x, v1.x, b1.x));
        pk[5] = (bf16)lrelu(fmaf(a1.y, v1.y, b1.y));
        pk[6] = (bf16)lrelu(fmaf(a1.z, v1.z, b1.z));
        pk[7] = (bf16)lrelu(fmaf(a1.w, v1.w, b1.w));
        *(bf16x8*)(h16 + (size_t)i * 8) = pk;
    }
}

// ======== per-node softmax aggregation: 64 threads/node, 2 adjacent cols/thread ========
// Each gather is a single 4B load (bf16 pair) -> half the VMEM instructions vs 128t version.
__global__ __launch_bounds__(64) void k_aggregate(const int2* __restrict__ es,
                                                  const int* __restrict__ cnt,
                                                  const bf16* __restrict__ h,
                                                  const bf16* __restrict__ attr16,
                                                  const float* __restrict__ tptr,
                                                  bf16* __restrict__ outpre) {
    const int node = blockIdx.x;
    const int p2 = threadIdx.x * 2;  // column pair (p2, p2+1)
    const float tv = tptr[0];
    const size_t o = (size_t)node * CAP;
    const int d = min(cnt[node], CAP);
    float den0 = 0.f, num0 = 0.f, den1 = 0.f, num1 = 0.f;
    unsigned a0 = 0, h0 = 0, a1 = 0, h1 = 0, a2 = 0, h2 = 0;
    unsigned a3 = 0, h3 = 0, a4 = 0, h4 = 0, a5 = 0, h5 = 0;
#define LOADJ(A, H, J)                                                       \
    if ((J) < d) {                                                           \
        int2 q = es[o + (J)];                                                \
        A = *(const unsigned*)(attr16 + (size_t)q.x * PD + p2);              \
        H = *(const unsigned*)(h + (size_t)q.y * PD + p2);                   \
    }
    LOADJ(a0, h0, 0) LOADJ(a1, h1, 1) LOADJ(a2, h2, 2)
    LOADJ(a3, h3, 3) LOADJ(a4, h4, 4) LOADJ(a5, h5, 5)
    for (int j = 0; j < d; ++j) {
        unsigned av = a0, hv = h0;
        a0 = a1; h0 = h1;
        a1 = a2; h1 = h2;
        a2 = a3; h2 = h3;
        a3 = a4; h3 = h4;
        a4 = a5; h4 = h5;
        if (j + 6 < d) {
            int2 q = es[o + j + 6];
            a5 = *(const unsigned*)(attr16 + (size_t)q.x * PD + p2);
            h5 = *(const unsigned*)(h + (size_t)q.y * PD + p2);
        }
        float m0 = bf_lo(hv) + bf_lo(av);
        float m1 = bf_hi(hv) + bf_hi(av);
        m0 = (m0 > 0.f ? m0 : 0.f) + 1e-7f;
        m1 = (m1 > 0.f ? m1 : 0.f) + 1e-7f;
        float w0 = __expf(m0 * tv);
        float w1 = __expf(m1 * tv);
        den0 += w0; num0 += m0 * w0;
        den1 += w1; num1 += m1 * w1;
    }
#undef LOADJ
    unsigned hp = *(const unsigned*)(h + (size_t)node * PD + p2);
    float r0 = (d > 0 ? num0 / den0 : 0.f) + bf_lo(hp);
    float r1 = (d > 0 ? num1 / den1 : 0.f) + bf_hi(hp);
    bf16 out2[2] = {(bf16)r0, (bf16)r1};
    *(unsigned*)(outpre + (size_t)node * PD + p2) = *(const unsigned*)out2;
}

// fallback (small workspace): recover attr = out1 - ea
__global__ __launch_bounds__(128) void k_aggregateF(const int2* __restrict__ es,
                                                    const int* __restrict__ cnt,
                                                    const bf16* __restrict__ h,
                                                    const float* __restrict__ out1,
                                                    const float* __restrict__ ea,
                                                    const float* __restrict__ tptr,
                                                    bf16* __restrict__ outpre) {
    const int node = blockIdx.x;
    const int p = threadIdx.x;
    const float tv = tptr[0];
    const size_t o = (size_t)node * CAP;
    const int d = min(cnt[node], CAP);
    float den = 0.f, num = 0.f;
    for (int j = 0; j < d; ++j) {
        int2 q = es[o + j];
        size_t idx = (size_t)q.x * PD + p;
        float av = out1[idx] - ea[idx];
        float msg = (float)h[(size_t)q.y * PD + p] + av;
        msg = (msg > 0.f ? msg : 0.f) + 1e-7f;
        float w = __expf(msg * tv);
        den += w;
        num += msg * w;
    }
    float hv = (float)h[(size_t)node * PD + p];
    float agg = (d > 0) ? num / den : 0.f;
    outpre[(size_t)node * PD + p] = (bf16)(agg + hv);
}

// ======== MLP: out0 = relu(LN(outpre @ W1^T)) @ W2^T + x ========
__global__ __launch_bounds__(256) void k_mlp(const bf16* __restrict__ outpre,
                                             const bf16* __restrict__ w116,
                                             const bf16* __restrict__ w216,
                                             const float* __restrict__ lng,
                                             const float* __restrict__ lnb,
                                             const float* __restrict__ x,
                                             float* __restrict__ out0) {
    __shared__ __align__(16) float SM[64][132];  // aliased as A2 (64x256 bf16)
    bf16* A2 = (bf16*)&SM[0][0];
    const int t = threadIdx.x, wave = t >> 6, lane = t & 63, g = lane >> 4, li = lane & 15;
    const size_t n0 = (size_t)blockIdx.x * 64;
    const int arow = (wave << 4) + li;
    f32x4 accY[16];
#pragma unroll
    for (int ct = 0; ct < 16; ++ct) accY[ct] = f32x4{0.f, 0.f, 0.f, 0.f};
#pragma unroll
    for (int ks = 0; ks < 4; ++ks) {
        int kb = ks * 32 + g * 8;
        bf16x8 af = *(const bf16x8*)(outpre + (n0 + arow) * PD + kb);
#pragma unroll
        for (int ct = 0; ct < 16; ++ct) {
            int col = (ct << 4) + li;
            bf16x8 bfr = *(const bf16x8*)(w116 + col * PD + kb);
            accY[ct] = __builtin_amdgcn_mfma_f32_16x16x32_bf16(af, bfr, accY[ct], 0, 0, 0);
        }
    }
#pragma unroll
    for (int j = 0; j < 4; ++j) {
        float s1 = 0.f, s2 = 0.f;
#pragma unroll
        for (int ct = 0; ct < 16; ++ct) {
            float v = accY[ct][j];
            s1 += v; s2 += v * v;
        }
        for (int o = 1; o < 16; o <<= 1) {
            s1 += __shfl_xor(s1, o);
            s2 += __shfl_xor(s2, o);
        }
        float mean = s1 * (1.f / HD);
        float var = s2 * (1.f / HD) - mean * mean;
        float rstd = rsqrtf(var + 1e-5f);
        int row = (wave << 4) + (g << 2) + j;
#pragma unroll
        for (int ct = 0; ct < 16; ++ct) {
            int col = (ct << 4) + li;
            float v = (accY[ct][j] - mean) * rstd;
            v = lng[col] * v + lnb[col];
            v = v > 0.f ? v : 0.f;
            A2[(row << 8) + (col ^ ((row & 7) << 3))] = (bf16)v;
        }
    }
    __syncthreads();
    f32x4 accZ[8];
#pragma unroll
    for (int ct = 0; ct < 8; ++ct) accZ[ct] = f32x4{0.f, 0.f, 0.f, 0.f};
#pragma unroll
    for (int ks = 0; ks < 8; ++ks) {
        int kb = ks * 32 + g * 8;
        bf16x8 af = *(const bf16x8*)&A2[(arow << 8) + (kb ^ ((arow & 7) << 3))];
#pragma unroll
        for (int ct = 0; ct < 8; ++ct) {
            int col = (ct << 4) + li;
            bf16x8 bfr = *(const bf16x8*)(w216 + col * HD + kb);
            accZ[ct] = __builtin_amdgcn_mfma_f32_16x16x32_bf16(af, bfr, accZ[ct], 0, 0, 0);
        }
    }
    __syncthreads();  // done reading A2
#pragma unroll
    for (int ct = 0; ct < 8; ++ct) {
        int col = (ct << 4) + li;
#pragma unroll
        for (int j = 0; j < 4; ++j) {
            int row = (wave << 4) + (g << 2) + j;
            SM[row][col] = accZ[ct][j];
        }
    }
    __syncthreads();
    {
        const size_t gb = n0 * PD;
#pragma unroll
        for (int i = 0; i < 8; ++i) {
            const int idx = i * 1024 + t * 4;
            const int row = idx >> 7, col = idx & 127;
            const size_t n = n0 + row;
            if (n < NN) {
                float4 r = *(const float4*)&SM[row][col];
                float4 xv = *(const float4*)(x + gb + idx);
                float4 w = {r.x + xv.x, r.y + xv.y, r.z + xv.z, r.w + xv.w};
                *(float4*)(out0 + gb + idx) = w;
            }
        }
    }
}

extern "C" void kernel_launch(void* const* d_in, const int* in_sizes, int n_in,
                              void* d_out, int out_size, void* d_ws, size_t ws_size,
                              hipStream_t stream) {
    const float* x = (const float*)d_in[0];
    const int* ei = (const int*)d_in[1];
    const float* ea = (const float*)d_in[2];
    const int* batch = (const int*)d_in[3];
    const float* gnw = (const float*)d_in[4];
    const float* gnb = (const float*)d_in[5];
    const float* gms = (const float*)d_in[6];
    const float* bng = (const float*)d_in[7];
    const float* bnb = (const float*)d_in[8];
    const float* pW = (const float*)d_in[9];
    const float* pb = (const float*)d_in[10];
    const float* tp = (const float*)d_in[11];
    const float* W1 = (const float*)d_in[12];
    const float* lng = (const float*)d_in[13];
    const float* lnb = (const float*)d_in[14];
    const float* W2 = (const float*)d_in[15];
    const int* srcI = ei;
    const int* dstI = ei + NE;
    float* out0 = (float*)d_out;
    float* out1 = out0 + (size_t)NN * PD;

    char* w = (char*)d_ws;
    size_t off = 0;
    auto alloc = [&](size_t bytes) -> char* {
        char* p = w + off;
        off += (bytes + 255) & ~(size_t)255;
        return p;
    };
    float* colsum = (float*)alloc(NBKT * PD * 4);
    float* colsq = (float*)alloc(NBKT * PD * 4);
    float* gsum = (float*)alloc(NG * PD * 4);
    float* gsq = (float*)alloc(NG * PD * 4);
    int* gcnt = (int*)alloc(NG * 4);
    int* cnt = (int*)alloc(NN * 4);
    size_t zero_bytes = off;  // everything above zeroed each call
    int2* es = (int2*)alloc((size_t)NN * CAP * 8);
    float* gA = (float*)alloc(NG * PD * 4);
    float* gB = (float*)alloc(NG * PD * 4);
    float* escale = (float*)alloc(PD * 4);
    float* eshift = (float*)alloc(PD * 4);
    bf16* pw16 = (bf16*)alloc(PD * PD * 2);
    bf16* w116 = (bf16*)alloc(HD * PD * 2);
    bf16* w216 = (bf16*)alloc(PD * HD * 2);
    bf16* h16 = (bf16*)alloc((size_t)NN * PD * 2);
    bf16* outpre = (bf16*)alloc((size_t)NPAD * PD * 2);
    size_t small_total = off;
    bf16* attr16 = (bf16*)alloc((size_t)NE * PD * 2);
    size_t big_total = off;
    if (ws_size < small_total) return;  // cannot run
    const bool big = (ws_size >= big_total);

    hipMemsetAsync(d_ws, 0, zero_bytes, stream);
    k_front<<<NB_BN + NB_GN + NB_SCAT + NB_CVT, 256, 0, stream>>>(
        ea, srcI, dstI, x, batch, pW, W1, W2, colsum, colsq, gsum, gsq, gcnt, cnt, es,
        pw16, w116, w216);
    k_mid<<<33, 256, 0, stream>>>(colsum, colsq, bng, bnb, escale, eshift,
                                  gsum, gsq, gcnt, gnw, gnb, gms, gA, gB);
    if (big) {
        k_big<true><<<NB_GEMM + NB_H, 256, 0, stream>>>(
            ea, escale, eshift, pw16, pb, attr16, out1, x, batch, gA, gB, h16);
        k_aggregate<<<NN, 64, 0, stream>>>(es, cnt, h16, attr16, tp, outpre);
    } else {
        k_big<false><<<NB_GEMM + NB_H, 256, 0, stream>>>(
            ea, escale, eshift, pw16, pb, nullptr, out1, x, batch, gA, gB, h16);
        k_aggregateF<<<NN, 128, 0, stream>>>(es, cnt, h16, out1, ea, tp, outpre);
    }
    k_mlp<<<NPAD / 64, 256, 0, stream>>>(outpre, w116, w216, lng, lnb, x, out0);
}